// Round 2
// baseline (1255.656 us; speedup 1.0000x reference)
//
#include <hip/hip_runtime.h>
#include <hip/hip_bf16.h>
#include <math.h>

// ---------- types ----------
typedef __attribute__((ext_vector_type(8))) short bf16x8;  // 8 bf16 (4 VGPRs)
typedef __attribute__((ext_vector_type(4))) float f32x4;   // MFMA C/D frag

__device__ inline float bf2f(short u) {
  union { float f; unsigned int i; } v;
  v.i = ((unsigned int)(unsigned short)u) << 16;
  return v.f;
}
__device__ inline short f2bf(float f) {
  union { float f; unsigned int i; } v; v.f = f;
  unsigned int r = v.i + 0x7fff + ((v.i >> 16) & 1);  // RNE
  return (short)(r >> 16);
}

// ---------- prep: pad/convert ----------
__global__ void pad_rows(const float* __restrict__ src, short* __restrict__ dst,
                         int C, int Cp, int total) {
  int i = blockIdx.x * 256 + threadIdx.x;
  if (i >= total) return;
  int r = i / Cp, c = i - r * Cp;
  dst[i] = f2bf(c < C ? src[(size_t)r * C + c] : 0.f);
}

__global__ void pad_T(const float* __restrict__ src, short* __restrict__ dst,
                      int K, int N, int Kp, int total) {
  int i = blockIdx.x * 256 + threadIdx.x;
  if (i >= total) return;
  int n = i / Kp, k = i - n * Kp;
  dst[i] = f2bf((k < K && n < N) ? src[(size_t)k * N + n] : 0.f);
}

// ---------- unified MFMA GEMM ----------
// A: bf16 [M x K] row-major. Bt: bf16 [N x K] (pre-transposed weights).
// Block: 512 thr = 8 waves, each wave 16 rows -> 128 rows/block. grid=(M/128, N/NT).
// MODE: 0 plain->bf16, 1 tanh(v+bias)->bf16, 2 relu(v+bias)->bf16, 3 v+bias->f32
template<int NT, int MODE>
__global__ __launch_bounds__(512) void gemm_ep(
    const short* __restrict__ A, const short* __restrict__ Bt, int K,
    const float* __restrict__ bias, int biasN,
    void* __restrict__ outp, int outStride)
{
  __shared__ __align__(16) short Bst[NT][40];  // [n][k-tile 32], row 80B: 2-way banks
  const int tid = threadIdx.x;
  const int wave = tid >> 6, lane = tid & 63;
  const int m = lane & 15, quad = lane >> 4;
  const int row0 = blockIdx.x * 128 + wave * 16;
  const int n0 = blockIdx.y * NT;

  f32x4 zero = {0.f, 0.f, 0.f, 0.f};
  f32x4 acc[NT / 16];
#pragma unroll
  for (int i = 0; i < NT / 16; ++i) acc[i] = zero;

  const short* arow = A + (size_t)(row0 + m) * K;

  for (int k0 = 0; k0 < K; k0 += 32) {
    __syncthreads();
    for (int idx = tid; idx < NT * 4; idx += 512) {
      int n = idx >> 2, kc = (idx & 3) << 3;
      *(uint4*)&Bst[n][kc] = *(const uint4*)&Bt[(size_t)(n0 + n) * K + k0 + kc];
    }
    __syncthreads();
    bf16x8 af = *(const bf16x8*)(arow + k0 + quad * 8);
#pragma unroll
    for (int nt = 0; nt < NT / 16; ++nt) {
      bf16x8 bf = *(const bf16x8*)&Bst[nt * 16 + m][quad * 8];
      acc[nt] = __builtin_amdgcn_mfma_f32_16x16x32_bf16(af, bf, acc[nt], 0, 0, 0);
    }
  }

#pragma unroll
  for (int nt = 0; nt < NT / 16; ++nt) {
#pragma unroll
    for (int r = 0; r < 4; ++r) {
      int row = row0 + quad * 4 + r;
      int col = n0 + nt * 16 + m;
      float v = acc[nt][r];
      if (MODE != 0) v += (col < biasN) ? bias[col] : 0.f;
      if (MODE == 1) v = tanhf(v);
      if (MODE == 2) v = fmaxf(v, 0.f);
      if (MODE == 3)
        ((float*)outp)[(size_t)row * outStride + col] = v;
      else
        ((short*)outp)[(size_t)row * outStride + col] = f2bf(v);
    }
  }
}

// ---------- LayerNorm over first 300 cols of a [rows x 320] bf16 buffer, in place ----------
__global__ __launch_bounds__(256) void ln_rows(short* __restrict__ tp,
                                               const float* __restrict__ g,
                                               const float* __restrict__ bb) {
  const int wave = threadIdx.x >> 6, lane = threadIdx.x & 63;
  const int row = blockIdx.x * 4 + wave;
  short* p = tp + (size_t)row * 320;
  float vals[5], s = 0.f, ss = 0.f;
#pragma unroll
  for (int i = 0; i < 5; ++i) {
    int c = lane + i * 64;
    float v = (c < 300) ? bf2f(p[c]) : 0.f;
    vals[i] = v; s += v; ss += v * v;
  }
#pragma unroll
  for (int off = 32; off > 0; off >>= 1) { s += __shfl_down(s, off); ss += __shfl_down(ss, off); }
  s = __shfl(s, 0); ss = __shfl(ss, 0);
  const float mu = s * (1.f / 300.f);
  const float rstd = rsqrtf(ss * (1.f / 300.f) - mu * mu + 1e-6f);
#pragma unroll
  for (int i = 0; i < 5; ++i) {
    int c = lane + i * 64;
    float v = (c < 300) ? (g[c] * (vals[i] - mu) * rstd + bb[c]) : 0.f;
    p[c] = f2bf(v);
  }
}

// ---------- fused sigmoid-attention ----------
// Out[b,s,d] = (tok ? tok[b,s,d] : 0) + sum_p sigmoid(Q[b,s,:]·K[b,p,:]) * V[b,p,d]
// All operands [64*1024 x 320] bf16 (cols 300..319 zero).
// Block: 256 thr = 4 waves, each wave 16 q-rows -> 64 q-rows/block. grid=(16, 64).
__global__ __launch_bounds__(256) void attn_fused(
    const short* __restrict__ Qm, const short* __restrict__ Km,
    const short* __restrict__ Vm, const short* __restrict__ tokp,
    short* __restrict__ Outp)
{
  __shared__ __align__(16) short Ks[32][328];   // [p][d] row 656B
  __shared__ __align__(16) short Vt[320][40];   // [d][p] row 80B (transposed V)
  __shared__ __align__(16) short Ps[4][16][40]; // per-wave P round-trip
  const int tid = threadIdx.x;
  const int wave = tid >> 6, lane = tid & 63;
  const int m = lane & 15, quad = lane >> 4;
  const int b = blockIdx.y;
  const int qrow0 = b * 1024 + blockIdx.x * 64 + wave * 16;
  const size_t kvbase = (size_t)b * 1024;

  // Q fragments in registers: 16 rows x 320 k
  bf16x8 qf[10];
#pragma unroll
  for (int c = 0; c < 10; ++c)
    qf[c] = *(const bf16x8*)&Qm[(size_t)(qrow0 + m) * 320 + c * 32 + quad * 8];

  f32x4 zero = {0.f, 0.f, 0.f, 0.f};
  f32x4 o[20];
#pragma unroll
  for (int i = 0; i < 20; ++i) o[i] = zero;

  for (int pt = 0; pt < 32; ++pt) {
    const size_t prow = kvbase + pt * 32;
    __syncthreads();
    // stage K tile (coalesced reads)
    for (int idx = tid; idx < 1280; idx += 256) {
      int p = idx / 40, dc = idx - p * 40;
      *(uint4*)&Ks[p][dc * 8] = *(const uint4*)&Km[(prow + p) * 320 + dc * 8];
    }
    // stage V tile transposed
    for (int idx = tid; idx < 1280; idx += 256) {
      int p = idx & 31, dc = idx >> 5;
      uint4 w = *(const uint4*)&Vm[(prow + p) * 320 + dc * 8];
      const short* wsp = (const short*)&w;
#pragma unroll
      for (int j = 0; j < 8; ++j) Vt[dc * 8 + j][p] = wsp[j];
    }
    __syncthreads();

    // S = Q·K^T : two 16x16 tiles covering 32 p
    f32x4 s0 = zero, s1 = zero;
#pragma unroll
    for (int c = 0; c < 10; ++c) {
      bf16x8 b0 = *(const bf16x8*)&Ks[m][c * 32 + quad * 8];
      bf16x8 b1 = *(const bf16x8*)&Ks[m + 16][c * 32 + quad * 8];
      s0 = __builtin_amdgcn_mfma_f32_16x16x32_bf16(qf[c], b0, s0, 0, 0, 0);
      s1 = __builtin_amdgcn_mfma_f32_16x16x32_bf16(qf[c], b1, s1, 0, 0, 0);
    }
    // sigmoid, write P (C-layout -> LDS)
#pragma unroll
    for (int r = 0; r < 4; ++r) {
      float v0 = 1.f / (1.f + __expf(-s0[r]));
      float v1 = 1.f / (1.f + __expf(-s1[r]));
      Ps[wave][quad * 4 + r][m] = f2bf(v0);
      Ps[wave][quad * 4 + r][m + 16] = f2bf(v1);
    }
    __syncthreads();
    // O += P·V
    bf16x8 pa = *(const bf16x8*)&Ps[wave][m][quad * 8];
#pragma unroll
    for (int nt = 0; nt < 20; ++nt) {
      bf16x8 vb = *(const bf16x8*)&Vt[nt * 16 + m][quad * 8];
      o[nt] = __builtin_amdgcn_mfma_f32_16x16x32_bf16(pa, vb, o[nt], 0, 0, 0);
    }
  }

#pragma unroll
  for (int nt = 0; nt < 20; ++nt) {
#pragma unroll
    for (int r = 0; r < 4; ++r) {
      int row = qrow0 + quad * 4 + r;
      int col = nt * 16 + m;
      float v = o[nt][r];
      if (tokp) v += bf2f(tokp[(size_t)row * 320 + col]);
      Outp[(size_t)row * 320 + col] = f2bf(v);
    }
  }
}

// ---------- launch ----------
extern "C" void kernel_launch(void* const* d_in, const int* in_sizes, int n_in,
                              void* d_out, int out_size, void* d_ws, size_t ws_size,
                              hipStream_t stream)
{
  const float* x    = (const float*)d_in[0];
  const float* me   = (const float*)d_in[1];
  const float* past = (const float*)d_in[2];
  const float* wpt  = (const float*)d_in[3];
  const float* bpt  = (const float*)d_in[4];
  const float* wpg  = (const float*)d_in[5];
  const float* bpg  = (const float*)d_in[6];
  const float* wps  = (const float*)d_in[7];
  const float* bps  = (const float*)d_in[8];
  const float* wex  = (const float*)d_in[9];
  const float* bex  = (const float*)d_in[10];
  const float* lng  = (const float*)d_in[11];
  const float* lnb  = (const float*)d_in[12];
  const float* W1   = (const float*)d_in[13];
  const float* b1   = (const float*)d_in[14];
  const float* W2   = (const float*)d_in[15];
  const float* b2   = (const float*)d_in[16];
  float* out = (float*)d_out;

  // ---- workspace layout (MUST stay < 256 MiB; R1 fix: 6 big bufs -> 4) ----
  char* ws = (char*)d_ws;
  size_t off = 0;
  auto alloc = [&](size_t bytes) -> char* {
    char* p = ws + off; off += (bytes + 255) & ~(size_t)255; return p;
  };
  const size_t RB = 65536ull;
  short* xp    = (short*)alloc(RB * 64 * 2);    //  8 MB
  short* pastp = (short*)alloc(RB * 64 * 2);    //  8 MB
  short* wmeT  = (short*)alloc(320 * 64 * 2);
  short* wptT  = (short*)alloc(320 * 64 * 2);
  short* wpgT  = (short*)alloc(320 * 64 * 2);
  short* wpsT  = (short*)alloc(320 * 64 * 2);
  short* wexT  = (short*)alloc(320 * 64 * 2);
  short* w1T   = (short*)alloc(320 * 320 * 2);
  short* w2T   = (short*)alloc(1024ull * 320 * 2);
  short* buf0  = (short*)alloc(RB * 320 * 2);   // 40 MB: ptok -> filt
  short* buf1  = (short*)alloc(RB * 320 * 2);   // 40 MB: pvec -> token
  short* buf2  = (short*)alloc(RB * 320 * 2);   // 40 MB: pstate -> evec
  short* buf3  = (short*)alloc(RB * 320 * 2);   // 40 MB: pre -> h
  // total ~177 MB

  // prep
  {
    int total = 65536 * 64;
    pad_rows<<<dim3((total + 255) / 256), 256, 0, stream>>>(x, xp, 50, 64, total);
    pad_rows<<<dim3((total + 255) / 256), 256, 0, stream>>>(past, pastp, 50, 64, total);
  }
  {
    int t = 320 * 64;
    dim3 g((t + 255) / 256);
    pad_T<<<g, 256, 0, stream>>>(me,  wmeT, 50, 300, 64, t);
    pad_T<<<g, 256, 0, stream>>>(wpt, wptT, 50, 300, 64, t);
    pad_T<<<g, 256, 0, stream>>>(wpg, wpgT, 50, 300, 64, t);
    pad_T<<<g, 256, 0, stream>>>(wps, wpsT, 50, 300, 64, t);
    pad_T<<<g, 256, 0, stream>>>(wex, wexT, 50, 300, 64, t);
  }
  { int t = 320 * 320;  pad_T<<<(t + 255) / 256, 256, 0, stream>>>(W1, w1T, 300, 300, 320, t); }
  { int t = 1024 * 320; pad_T<<<(t + 255) / 256, 256, 0, stream>>>(W2, w2T, 300, 1024, 320, t); }

  dim3 g512(512, 1);
  // attention-1 operands
  gemm_ep<320, 1><<<g512, 512, 0, stream>>>(xp,    wptT, 64, bpt, 300, buf0, 320); // ptok
  gemm_ep<320, 1><<<g512, 512, 0, stream>>>(pastp, wpgT, 64, bpg, 300, buf1, 320); // pvec
  gemm_ep<320, 1><<<g512, 512, 0, stream>>>(pastp, wpsT, 64, bps, 300, buf2, 320); // pstate

  // attention 1: pre = sigmoid(ptok.pvec^T).pstate
  attn_fused<<<dim3(16, 64), 256, 0, stream>>>(buf0, buf1, buf2, nullptr, buf3);

  // token (buf1: pvec dead), evec (buf2: pstate dead)
  gemm_ep<320, 0><<<g512, 512, 0, stream>>>(xp, wmeT, 64, nullptr, 0, buf1, 320);
  ln_rows<<<16384, 256, 0, stream>>>(buf1, lng, lnb);
  gemm_ep<320, 1><<<g512, 512, 0, stream>>>(xp, wexT, 64, bex, 300, buf2, 320);

  // attention 2: filt = token + sigmoid(evec.pre^T).pre   (buf0: ptok dead)
  attn_fused<<<dim3(16, 64), 256, 0, stream>>>(buf2, buf3, buf3, buf1, buf0);

  // MLP: h = relu(filt@W1+b1) (buf3: pre dead), out = h@W2+b2
  gemm_ep<320, 2><<<g512, 512, 0, stream>>>(buf0, w1T, 320, b1, 300, buf3, 320);
  gemm_ep<256, 3><<<dim3(512, 4), 512, 0, stream>>>(buf3, w2T, 320, b2, 1024, out, 1024);
}

// Round 3
// 1139.551 us; speedup vs baseline: 1.1019x; 1.1019x over previous
//
#include <hip/hip_runtime.h>
#include <hip/hip_bf16.h>
#include <math.h>

// ---------- types ----------
typedef __attribute__((ext_vector_type(8))) short bf16x8;  // 8 bf16 (4 VGPRs)
typedef __attribute__((ext_vector_type(4))) float f32x4;   // MFMA C/D frag

__device__ inline float bf2f(short u) {
  union { float f; unsigned int i; } v;
  v.i = ((unsigned int)(unsigned short)u) << 16;
  return v.f;
}
__device__ inline short f2bf(float f) {
  union { float f; unsigned int i; } v; v.f = f;
  unsigned int r = v.i + 0x7fff + ((v.i >> 16) & 1);  // RNE
  return (short)(r >> 16);
}

// ---------- prep: pad/convert ----------
__global__ void pad_rows(const float* __restrict__ src, short* __restrict__ dst,
                         int C, int Cp, int total) {
  int i = blockIdx.x * 256 + threadIdx.x;
  if (i >= total) return;
  int r = i / Cp, c = i - r * Cp;
  dst[i] = f2bf(c < C ? src[(size_t)r * C + c] : 0.f);
}

__global__ void pad_T(const float* __restrict__ src, short* __restrict__ dst,
                      int K, int N, int Kp, int total) {
  int i = blockIdx.x * 256 + threadIdx.x;
  if (i >= total) return;
  int n = i / Kp, k = i - n * Kp;
  dst[i] = f2bf((k < K && n < N) ? src[(size_t)k * N + n] : 0.f);
}

// ---------- batched transpose: in [64][1024][320] -> out [64][320][1024] ----------
// 64p x 64d tiles; LDS stored as dwords with XOR swizzle (conflict-light both phases).
__global__ __launch_bounds__(256) void transpose_pd(const short* __restrict__ in,
                                                    short* __restrict__ out) {
  __shared__ unsigned int T[64][32];  // row p: 32 dwords (64 shorts)
  const int b = blockIdx.z, p0 = blockIdx.x * 64, d0 = blockIdx.y * 64;
  const short* ib = in + (size_t)b * 1024 * 320;
  short* ob = out + (size_t)b * 320 * 1024;
  for (int i = threadIdx.x; i < 512; i += 256) {
    int p = i >> 3, g = i & 7;
    uint4 v = *(const uint4*)&ib[(size_t)(p0 + p) * 320 + d0 + g * 8];
    int s = p & 31;
    T[p][(4 * g + 0) ^ s] = v.x;
    T[p][(4 * g + 1) ^ s] = v.y;
    T[p][(4 * g + 2) ^ s] = v.z;
    T[p][(4 * g + 3) ^ s] = v.w;
  }
  __syncthreads();
  for (int i = threadIdx.x; i < 512; i += 256) {
    int d = i >> 3, g = i & 7;
    int w0 = d >> 1;
    __align__(16) unsigned short tmp[8];
#pragma unroll
    for (int j = 0; j < 8; ++j) {
      int p = g * 8 + j;
      unsigned int val = T[p][w0 ^ (p & 31)];
      tmp[j] = (d & 1) ? (unsigned short)(val >> 16) : (unsigned short)(val & 0xffff);
    }
    *(uint4*)&ob[(size_t)(d0 + d) * 1024 + p0 + g * 8] = *(const uint4*)tmp;
  }
}

// ---------- unified MFMA GEMM ----------
// A: bf16 [M x K] row-major. Bt: bf16 [N x K] (pre-transposed weights).
// Block: 512 thr = 8 waves, each wave 16 rows -> 128 rows/block. grid=(M/128, N/NT).
// MODE: 0 plain->bf16, 1 tanh(v+bias)->bf16, 2 relu(v+bias)->bf16, 3 v+bias->f32
template<int NT, int MODE>
__global__ __launch_bounds__(512) void gemm_ep(
    const short* __restrict__ A, const short* __restrict__ Bt, int K,
    const float* __restrict__ bias, int biasN,
    void* __restrict__ outp, int outStride)
{
  __shared__ __align__(16) short Bst[NT][40];  // [n][k-tile 32], row 80B
  const int tid = threadIdx.x;
  const int wave = tid >> 6, lane = tid & 63;
  const int m = lane & 15, quad = lane >> 4;
  const int row0 = blockIdx.x * 128 + wave * 16;
  const int n0 = blockIdx.y * NT;

  f32x4 zero = {0.f, 0.f, 0.f, 0.f};
  f32x4 acc[NT / 16];
#pragma unroll
  for (int i = 0; i < NT / 16; ++i) acc[i] = zero;

  const short* arow = A + (size_t)(row0 + m) * K;

  for (int k0 = 0; k0 < K; k0 += 32) {
    __syncthreads();
    for (int idx = tid; idx < NT * 4; idx += 512) {
      int n = idx >> 2, kc = (idx & 3) << 3;
      *(uint4*)&Bst[n][kc] = *(const uint4*)&Bt[(size_t)(n0 + n) * K + k0 + kc];
    }
    __syncthreads();
    bf16x8 af = *(const bf16x8*)(arow + k0 + quad * 8);
#pragma unroll
    for (int nt = 0; nt < NT / 16; ++nt) {
      bf16x8 bf = *(const bf16x8*)&Bst[nt * 16 + m][quad * 8];
      acc[nt] = __builtin_amdgcn_mfma_f32_16x16x32_bf16(af, bf, acc[nt], 0, 0, 0);
    }
  }

#pragma unroll
  for (int nt = 0; nt < NT / 16; ++nt) {
#pragma unroll
    for (int r = 0; r < 4; ++r) {
      int row = row0 + quad * 4 + r;
      int col = n0 + nt * 16 + m;
      float v = acc[nt][r];
      if (MODE != 0) v += (col < biasN) ? bias[col] : 0.f;
      if (MODE == 1) v = tanhf(v);
      if (MODE == 2) v = fmaxf(v, 0.f);
      if (MODE == 3)
        ((float*)outp)[(size_t)row * outStride + col] = v;
      else
        ((short*)outp)[(size_t)row * outStride + col] = f2bf(v);
    }
  }
}

// ---------- LayerNorm over first 300 cols of a [rows x 320] bf16 buffer, in place ----------
__global__ __launch_bounds__(256) void ln_rows(short* __restrict__ tp,
                                               const float* __restrict__ g,
                                               const float* __restrict__ bb) {
  const int wave = threadIdx.x >> 6, lane = threadIdx.x & 63;
  const int row = blockIdx.x * 4 + wave;
  short* p = tp + (size_t)row * 320;
  float vals[5], s = 0.f, ss = 0.f;
#pragma unroll
  for (int i = 0; i < 5; ++i) {
    int c = lane + i * 64;
    float v = (c < 300) ? bf2f(p[c]) : 0.f;
    vals[i] = v; s += v; ss += v * v;
  }
#pragma unroll
  for (int off = 32; off > 0; off >>= 1) { s += __shfl_down(s, off); ss += __shfl_down(ss, off); }
  s = __shfl(s, 0); ss = __shfl(ss, 0);
  const float mu = s * (1.f / 300.f);
  const float rstd = rsqrtf(ss * (1.f / 300.f) - mu * mu + 1e-6f);
#pragma unroll
  for (int i = 0; i < 5; ++i) {
    int c = lane + i * 64;
    float v = (c < 300) ? (g[c] * (vals[i] - mu) * rstd + bb[c]) : 0.f;
    p[c] = f2bf(v);
  }
}

// ---------- fused sigmoid-attention v2 ----------
// Out[b,s,:] = (tok? tok[b,s,:] : 0) + sum_p sigmoid(Q[b,s,:].K[b,p,:]) * V[b,p,:]
// Q,K,tok,Out: [64*1024 x 320] bf16 row-major. VT: per-batch [320][1024] (V transposed).
// Block 512 thr = 8 waves, 128 q-rows. Grid (64 batches, 8 q-blocks):
// linear id = b + 64*qb -> XCD = b%8: all q-blocks of a batch share an XCD L2.
__global__ __launch_bounds__(512) void attn_v2(
    const short* __restrict__ Qm, const short* __restrict__ Km,
    const short* __restrict__ VT, const short* __restrict__ tokp,
    short* __restrict__ Outp)
{
  __shared__ __align__(16) short Ks[32][328];   // 20,992 B
  __shared__ __align__(16) short Vt[320][40];   // 25,600 B
  __shared__ __align__(16) short Ps[8][16][40]; // 10,240 B  (per-wave P round-trip)
  const int tid = threadIdx.x;
  const int wave = tid >> 6, lane = tid & 63;
  const int m = lane & 15, quad = lane >> 4;
  const int b = blockIdx.x;
  const int qrow0 = b * 1024 + blockIdx.y * 128 + wave * 16;
  const size_t kbase = (size_t)b * 1024 * 320;
  const short* vtb = VT + (size_t)b * 320 * 1024;

  // Q fragments in registers: 16 rows x 320 k
  bf16x8 qf[10];
#pragma unroll
  for (int c = 0; c < 10; ++c)
    qf[c] = *(const bf16x8*)&Qm[(size_t)(qrow0 + m) * 320 + c * 32 + quad * 8];

  f32x4 zero = {0.f, 0.f, 0.f, 0.f};
  f32x4 o[20];
#pragma unroll
  for (int i = 0; i < 20; ++i) o[i] = zero;

  for (int pt = 0; pt < 32; ++pt) {
    const int p0 = pt * 32;
    __syncthreads();
    // stage K tile: 32 p-rows x 40 uint4  (coalesced, b128 LDS writes)
    for (int idx = tid; idx < 1280; idx += 512) {
      int p = idx / 40, g = idx - p * 40;
      *(uint4*)&Ks[p][g * 8] = *(const uint4*)&Km[kbase + (size_t)(p0 + p) * 320 + g * 8];
    }
    // stage V^T tile: 320 d-rows x 4 uint4 (pre-transposed global: b128 both sides)
    for (int idx = tid; idx < 1280; idx += 512) {
      int d = idx >> 2, g = idx & 3;
      *(uint4*)&Vt[d][g * 8] = *(const uint4*)&vtb[(size_t)d * 1024 + p0 + g * 8];
    }
    __syncthreads();

    // S = Q.K^T : two 16x16 tiles covering 32 p
    f32x4 s0 = zero, s1 = zero;
#pragma unroll
    for (int c = 0; c < 10; ++c) {
      bf16x8 b0 = *(const bf16x8*)&Ks[m][c * 32 + quad * 8];
      bf16x8 b1 = *(const bf16x8*)&Ks[m + 16][c * 32 + quad * 8];
      s0 = __builtin_amdgcn_mfma_f32_16x16x32_bf16(qf[c], b0, s0, 0, 0, 0);
      s1 = __builtin_amdgcn_mfma_f32_16x16x32_bf16(qf[c], b1, s1, 0, 0, 0);
    }
    // sigmoid -> Ps (wave-private round-trip: NO block barrier needed)
#pragma unroll
    for (int r = 0; r < 4; ++r) {
      float v0 = 1.f / (1.f + __expf(-s0[r]));
      float v1 = 1.f / (1.f + __expf(-s1[r]));
      Ps[wave][quad * 4 + r][m] = f2bf(v0);
      Ps[wave][quad * 4 + r][m + 16] = f2bf(v1);
    }
    // O += P.V
    bf16x8 pa = *(const bf16x8*)&Ps[wave][m][quad * 8];
#pragma unroll
    for (int nt = 0; nt < 20; ++nt) {
      bf16x8 vb = *(const bf16x8*)&Vt[nt * 16 + m][quad * 8];
      o[nt] = __builtin_amdgcn_mfma_f32_16x16x32_bf16(pa, vb, o[nt], 0, 0, 0);
    }
  }

#pragma unroll
  for (int nt = 0; nt < 20; ++nt) {
#pragma unroll
    for (int r = 0; r < 4; ++r) {
      int row = qrow0 + quad * 4 + r;
      int col = nt * 16 + m;
      float v = o[nt][r];
      if (tokp) v += bf2f(tokp[(size_t)row * 320 + col]);
      Outp[(size_t)row * 320 + col] = f2bf(v);
    }
  }
}

// ---------- launch ----------
extern "C" void kernel_launch(void* const* d_in, const int* in_sizes, int n_in,
                              void* d_out, int out_size, void* d_ws, size_t ws_size,
                              hipStream_t stream)
{
  const float* x    = (const float*)d_in[0];
  const float* me   = (const float*)d_in[1];
  const float* past = (const float*)d_in[2];
  const float* wpt  = (const float*)d_in[3];
  const float* bpt  = (const float*)d_in[4];
  const float* wpg  = (const float*)d_in[5];
  const float* bpg  = (const float*)d_in[6];
  const float* wps  = (const float*)d_in[7];
  const float* bps  = (const float*)d_in[8];
  const float* wex  = (const float*)d_in[9];
  const float* bex  = (const float*)d_in[10];
  const float* lng  = (const float*)d_in[11];
  const float* lnb  = (const float*)d_in[12];
  const float* W1   = (const float*)d_in[13];
  const float* b1   = (const float*)d_in[14];
  const float* W2   = (const float*)d_in[15];
  const float* b2   = (const float*)d_in[16];
  float* out = (float*)d_out;

  // ---- workspace (~226 MB; stay under ~268 MB) ----
  char* ws = (char*)d_ws;
  size_t off = 0;
  auto alloc = [&](size_t bytes) -> char* {
    char* p = ws + off; off += (bytes + 255) & ~(size_t)255; return p;
  };
  const size_t RB = 65536ull;
  short* xp    = (short*)alloc(RB * 64 * 2);    //  8 MB
  short* pastp = (short*)alloc(RB * 64 * 2);    //  8 MB
  short* wmeT  = (short*)alloc(320 * 64 * 2);
  short* wptT  = (short*)alloc(320 * 64 * 2);
  short* wpgT  = (short*)alloc(320 * 64 * 2);
  short* wpsT  = (short*)alloc(320 * 64 * 2);
  short* wexT  = (short*)alloc(320 * 64 * 2);
  short* w1T   = (short*)alloc(320 * 320 * 2);
  short* w2T   = (short*)alloc(1024ull * 320 * 2);
  short* buf0  = (short*)alloc(RB * 320 * 2);   // 40 MB: ptok -> filt
  short* buf1  = (short*)alloc(RB * 320 * 2);   // 40 MB: pvec -> token
  short* buf2  = (short*)alloc(RB * 320 * 2);   // 40 MB: pstate -> evec
  short* buf3  = (short*)alloc(RB * 320 * 2);   // 40 MB: pre -> h
  short* vtbuf = (short*)alloc(RB * 320 * 2);   // 40 MB: pstate^T -> pre^T

  // prep
  {
    int total = 65536 * 64;
    pad_rows<<<dim3((total + 255) / 256), 256, 0, stream>>>(x, xp, 50, 64, total);
    pad_rows<<<dim3((total + 255) / 256), 256, 0, stream>>>(past, pastp, 50, 64, total);
  }
  {
    int t = 320 * 64;
    dim3 g((t + 255) / 256);
    pad_T<<<g, 256, 0, stream>>>(me,  wmeT, 50, 300, 64, t);
    pad_T<<<g, 256, 0, stream>>>(wpt, wptT, 50, 300, 64, t);
    pad_T<<<g, 256, 0, stream>>>(wpg, wpgT, 50, 300, 64, t);
    pad_T<<<g, 256, 0, stream>>>(wps, wpsT, 50, 300, 64, t);
    pad_T<<<g, 256, 0, stream>>>(wex, wexT, 50, 300, 64, t);
  }
  { int t = 320 * 320;  pad_T<<<(t + 255) / 256, 256, 0, stream>>>(W1, w1T, 300, 300, 320, t); }
  { int t = 1024 * 320; pad_T<<<(t + 255) / 256, 256, 0, stream>>>(W2, w2T, 300, 1024, 320, t); }

  dim3 g512(512, 1);
  dim3 tgrid(16, 5, 64);
  // attention-1 operands
  gemm_ep<320, 1><<<g512, 512, 0, stream>>>(xp,    wptT, 64, bpt, 300, buf0, 320); // ptok
  gemm_ep<320, 1><<<g512, 512, 0, stream>>>(pastp, wpgT, 64, bpg, 300, buf1, 320); // pvec
  gemm_ep<320, 1><<<g512, 512, 0, stream>>>(pastp, wpsT, 64, bps, 300, buf2, 320); // pstate
  transpose_pd<<<tgrid, 256, 0, stream>>>(buf2, vtbuf);                            // pstate^T

  // attention 1: pre = sigmoid(ptok.pvec^T).pstate
  attn_v2<<<dim3(64, 8), 512, 0, stream>>>(buf0, buf1, vtbuf, nullptr, buf3);

  // token (buf1: pvec dead), evec (buf2: pstate dead)
  gemm_ep<320, 0><<<g512, 512, 0, stream>>>(xp, wmeT, 64, nullptr, 0, buf1, 320);
  ln_rows<<<16384, 256, 0, stream>>>(buf1, lng, lnb);
  gemm_ep<320, 1><<<g512, 512, 0, stream>>>(xp, wexT, 64, bex, 300, buf2, 320);

  // pre^T (overwrites pstate^T)
  transpose_pd<<<tgrid, 256, 0, stream>>>(buf3, vtbuf);

  // attention 2: filt = token + sigmoid(evec.pre^T).pre   (buf0: ptok dead)
  attn_v2<<<dim3(64, 8), 512, 0, stream>>>(buf2, buf3, vtbuf, buf1, buf0);

  // MLP: h = relu(filt@W1+b1) (buf3: pre dead), out = h@W2+b2
  gemm_ep<320, 2><<<g512, 512, 0, stream>>>(buf0, w1T, 320, b1, 300, buf3, 320);
  gemm_ep<256, 3><<<dim3(512, 4), 512, 0, stream>>>(buf3, w2T, 320, b2, 1024, out, 1024);
}